// Round 8
// baseline (66.587 us; speedup 1.0000x reference)
//
#include <hip/hip_runtime.h>
#include <math.h>

#define BATCH 2
#define NDIRS 64
#define NCH   630
#define MPAD  640
#define HW    16384         // 128*128
#define KDIR  384           // 64 dirs * 6 moments
#define NT    12            // k-steps of 32
#define PANEL 128           // px per block (512B HBM read segments)
#define NPOSW 5             // m-positions (32 rows) per wave
#define NITER (NPOSW * NT)  // 60
#define BROWE 392           // Bs row stride in ushorts (784B)

// LDS layout (dynamic, 104960 B; 1 block/CU, 8 waves)
#define BS_OFF 0            // 128 * 392 * 2      = 100352
#define TV_OFF 100352       // 640 * 4            =   2560
#define TG_OFF 102912       // 4 * 128 * 4        =   2048
#define LDS_TOTAL 104960

typedef float f32x4 __attribute__((ext_vector_type(4)));
typedef short s16x8 __attribute__((ext_vector_type(8)));
typedef uint  u32x4 __attribute__((ext_vector_type(4)));

__device__ __forceinline__ uint cvt_pk_bf16(float lo, float hi) {
    uint r;
    asm("v_cvt_pk_bf16_f32 %0, %1, %2" : "=v"(r) : "v"(lo), "v"(hi));
    return r;
}

// nontemporal 16B load: TD stream has ZERO intra-kernel reuse -> do not
// allocate in L2 (protects L2-resident P and the small t/b vectors).
__device__ __forceinline__ f32x4 ntload(const float* p) {
    return __builtin_nontemporal_load((const f32x4*)p);
}

// ---------------------------------------------------------------------------
// SINGLE fused kernel (R8): prep_kernel + W2b workspace ELIMINATED.
// The GEMM k-sum is order-invariant, so both operands use the permuted
// index k' = kk*64 + d  (kk = moment 0..5, d = direction 0..63) instead of
// k = d*6 + kk. Consequences:
//   A-side: a fragment (8 consecutive k' at K0 = ti*32+lhi*8) has
//     kk = ti>>1 (COMPILE-TIME) and d = d0..d0+7 consecutive, so
//     A-frag = cf[kk](c) * P[c][d0..d0+8)  -- two dwordx4 L2-hot loads of
//     the P row + 8 muls + 4 cvt_pk packs. No prep, no gather, no
//     runtime-indexed arrays (rule #20 safe).
//   B-side: staging machinery (swizzle, slots, depth-3 prefetch) is
//     unchanged in k'-space; only the TD source rows change:
//     step S stages k'-rows S*32 + {2kq2, 2kq2+1} whose TD flat rows are
//     12*kq2 + (S&1)*192 + (S>>1) + {0, 6}. Same 256B/wave read segments,
//     rows were already 64KB apart -> DRAM locality unchanged.
// Coeffs cf[2][6] refresh per position at the prefetch boundary (COEF
// before ITER 10/22/34/46); rows >= 630 are address-clamped and their
// coeffs auto-zero (every coeff has a factor of b, and stores are guarded).
// P-loads issue at ITER-top; pack happens AFTER the MFMA block
// (sched_barrier-pinned) so L2 latency hides under the MFMAs.
// Everything else is byte-identical to the R2 champion (nt+64B stores).
// ---------------------------------------------------------------------------
__global__ __launch_bounds__(512, 2) void fused_gemm(
        const float* __restrict__ P,      // [NCH][64] f32 (L2-resident)
        const float* __restrict__ TD,     // [B][KDIR][HW] f32 (theta_dir)
        const float* __restrict__ t_vec,  // [NCH]
        const float* __restrict__ b_vec,  // [NCH]
        const float* __restrict__ TG,     // [B][4][HW]
        float* __restrict__ out)          // [B][NCH][HW]
{
    extern __shared__ char lds[];

    const int nt_ = blockIdx.x;           // 0..127 (128-px panel)
    const int bz  = blockIdx.y;           // 0..1
    const int n0  = nt_ * PANEL;

    const int tid  = threadIdx.x;         // 0..511
    const int lane = tid & 63;
    const int wv   = tid >> 6;            // 0..7
    const int mg   = wv & 3;              // A row group (c = mg*160 + ...)
    const int w    = wv >> 2;             // px half (0/1)
    const int l15 = lane & 15, lhi = lane >> 4;
    const int lhi8 = lhi << 3;

    ushort* bsU = (ushort*)(lds + BS_OFF);
    float*  tvl = (float*)(lds + TV_OFF);
    float*  tgl = (float*)(lds + TG_OFF);

    // ---- stage t_vec -> LDS (OOB-safe; for EPIs) ----
    tvl[tid] = t_vec[tid];
    if (tid < NCH - 512) tvl[tid + 512] = t_vec[tid + 512];
    else if (tid + 512 < MPAD) tvl[tid + 512] = 0.0f;
    // ---- stage TG (4 planes x 128 px) ----
    {
        int p = tid >> 7, px = tid & 127;
        tgl[p * PANEL + px] = TG[((size_t)bz * 4 + p) * HW + n0 + px];
    }

    // ---- per-position A coefficient state ----
    float cfA[6], cfB[6];
    const float *pA0, *pA1;

#define COEF(P_)                                                               \
    {                                                                          \
        int c0_ = mg * 160 + (P_) * 32 + l15;                                  \
        int cA_ = (c0_ < NCH) ? c0_ : (NCH - 1);                               \
        int cB_ = (c0_ + 16 < NCH) ? (c0_ + 16) : (NCH - 1);                   \
        float t0_ = t_vec[cA_], b0_ = b_vec[cA_];                              \
        float t1_ = t_vec[cB_], b1_ = b_vec[cB_];                              \
        cfA[0] = -b0_;                     cfB[0] = -b1_;                      \
        cfA[1] = t0_ * b0_;                cfB[1] = t1_ * b1_;                 \
        cfA[2] = 0.5f * b0_ * b0_;         cfB[2] = 0.5f * b1_ * b1_;          \
        cfA[3] = -0.5f * t0_ * t0_ * b0_;  cfB[3] = -0.5f * t1_ * t1_ * b1_;   \
        cfA[4] = -0.5f * t0_ * b0_ * b0_;  cfB[4] = -0.5f * t1_ * b1_ * b1_;   \
        cfA[5] = -(1.0f/6.0f) * b0_ * b0_ * b0_;                               \
        cfB[5] = -(1.0f/6.0f) * b1_ * b1_ * b1_;                               \
        pA0 = P + cA_ * 64;                                                    \
        pA1 = P + cB_ * 64;                                                    \
    }

    s16x8 afb[3][2];

// full A-frag generation (load+mul+pack in one shot; init only)
#define AFINIT(NB_, TI_)                                                       \
    {                                                                          \
        constexpr int kk_ = (TI_) >> 1;                                        \
        const int d0_ = (((TI_) & 1) << 5) + lhi8;                             \
        f32x4 qa0_ = *(const f32x4*)(pA0 + d0_);                               \
        f32x4 qa1_ = *(const f32x4*)(pA0 + d0_ + 4);                           \
        f32x4 qb0_ = *(const f32x4*)(pA1 + d0_);                               \
        f32x4 qb1_ = *(const f32x4*)(pA1 + d0_ + 4);                           \
        float ca_ = cfA[kk_], cb_ = cfB[kk_];                                  \
        u32x4 ua_, ub_;                                                        \
        ua_[0] = cvt_pk_bf16(ca_*qa0_[0], ca_*qa0_[1]);                        \
        ua_[1] = cvt_pk_bf16(ca_*qa0_[2], ca_*qa0_[3]);                        \
        ua_[2] = cvt_pk_bf16(ca_*qa1_[0], ca_*qa1_[1]);                        \
        ua_[3] = cvt_pk_bf16(ca_*qa1_[2], ca_*qa1_[3]);                        \
        ub_[0] = cvt_pk_bf16(cb_*qb0_[0], cb_*qb0_[1]);                        \
        ub_[1] = cvt_pk_bf16(cb_*qb0_[2], cb_*qb0_[3]);                        \
        ub_[2] = cvt_pk_bf16(cb_*qb1_[0], cb_*qb1_[1]);                        \
        ub_[3] = cvt_pk_bf16(cb_*qb1_[2], cb_*qb1_[3]);                        \
        afb[NB_][0] = __builtin_bit_cast(s16x8, ua_);                          \
        afb[NB_][1] = __builtin_bit_cast(s16x8, ub_);                          \
    }

    // ---- position-0 coeffs + first two iterations' A-frags ----
    COEF(0)
    AFINIT(0, 0)
    AFINIT(1, 1)
    __builtin_amdgcn_sched_barrier(0);

    // ---- stage B panel: 12 k'-steps, depth-3 reg prefetch (NT loads) ----
    // kq2 = mg*4+lhi (0..15): k'-row pair {2kq2, 2kq2+1} per 32-step
    // pg  = w*16+l15  (0..31): px group pg*4 .. pg*4+3
    const int kq2 = mg * 4 + lhi;
    const int pg  = w * 16 + l15;
    const float* bT = TD + (size_t)bz * KDIR * HW + (size_t)(12 * kq2) * HW
                      + n0 + pg * 4;
    const int sxor = ((kq2 >> 2) ^ (pg & 3) ^ ((pg >> 2) & 3)) & 3;
    const int wbase = (kq2 & 3) * 2;      // uint pos within 8-ushort slot

#define BOFF(S) ((size_t)((((S) & 1) * 192) + ((S) >> 1)) * HW)

    {
        f32x4 lo0, hi0, lo1, hi1, lo2, hi2, lo3, hi3;
        lo0 = ntload(bT + BOFF(0));
        hi0 = ntload(bT + BOFF(0) + 6 * HW);
        lo1 = ntload(bT + BOFF(1));
        hi1 = ntload(bT + BOFF(1) + 6 * HW);
        lo2 = ntload(bT + BOFF(2));
        hi2 = ntload(bT + BOFF(2) + 6 * HW);

#define BSTEP(S, LC, HC, LN, HN)                                               \
        {                                                                      \
            if ((S) + 3 < NT) {                                                \
                LN = ntload(bT + BOFF((S) + 3));                               \
                HN = ntload(bT + BOFF((S) + 3) + 6 * HW);                      \
            }                                                                  \
            _Pragma("unroll")                                                  \
            for (int i = 0; i < 4; ++i) {                                      \
                uint w_ = cvt_pk_bf16(LC[i], HC[i]);                           \
                int s_ = (sxor ^ i) & 3;                                       \
                *(uint*)&bsU[(pg * 4 + i) * BROWE + (S) * 32 + s_ * 8 + wbase] = w_; \
            }                                                                  \
        }
        BSTEP(0, lo0, hi0, lo3, hi3)  BSTEP(1, lo1, hi1, lo0, hi0)
        BSTEP(2, lo2, hi2, lo1, hi1)  BSTEP(3, lo3, hi3, lo2, hi2)
        BSTEP(4, lo0, hi0, lo3, hi3)  BSTEP(5, lo1, hi1, lo0, hi0)
        BSTEP(6, lo2, hi2, lo1, hi1)  BSTEP(7, lo3, hi3, lo2, hi2)
        BSTEP(8, lo0, hi0, lo3, hi3)  BSTEP(9, lo1, hi1, lo0, hi0)
        BSTEP(10, lo2, hi2, lo1, hi1) BSTEP(11, lo3, hi3, lo2, hi2)
#undef BSTEP
    }

    // ---- single barrier: Bs/tv/tg visible ----
    asm volatile("s_waitcnt lgkmcnt(0)" ::: "memory");
    __builtin_amdgcn_s_barrier();
    __builtin_amdgcn_sched_barrier(0);

    // hoist TG values (wave covers its 64-px half: px = w*64 + n*16 + l15)
    float gg[4][4];
    #pragma unroll
    for (int n = 0; n < 4; ++n)
        #pragma unroll
        for (int p = 0; p < 4; ++p)
            gg[n][p] = tgl[p * PANEL + w * 64 + n * 16 + l15];

    f32x4 acc[2][4];
    #pragma unroll
    for (int m = 0; m < 2; ++m)
        #pragma unroll
        for (int n = 0; n < 4; ++n) acc[m][n] = (f32x4){0.f, 0.f, 0.f, 0.f};

    // ---- 60-iter pipeline; A-frag gen split: P-loads at top (issue early),
    //      pack after MFMAs (L2 latency hides under the MFMA block) ----
#define ITER(G)                                                                \
    {                                                                          \
        constexpr int T_ = (G) % NT, buf_ = (G) % 3;                           \
        constexpr int gn_ = (G) + 2;                                           \
        constexpr int ti_ = gn_ % NT, nb_ = gn_ % 3;                           \
        constexpr int kk_ = ti_ >> 1;                                          \
        f32x4 qa0_, qa1_, qb0_, qb1_;                                          \
        if constexpr (gn_ < NITER) {                                           \
            const int d0_ = ((ti_ & 1) << 5) + lhi8;                           \
            qa0_ = *(const f32x4*)(pA0 + d0_);                                 \
            qa1_ = *(const f32x4*)(pA0 + d0_ + 4);                             \
            qb0_ = *(const f32x4*)(pA1 + d0_);                                 \
            qb1_ = *(const f32x4*)(pA1 + d0_ + 4);                             \
            __builtin_amdgcn_sched_barrier(0);                                 \
        }                                                                      \
        s16x8 bf[4];                                                           \
        _Pragma("unroll")                                                      \
        for (int n = 0; n < 4; ++n) {                                          \
            const int rs_ = (lhi ^ (l15 & 3) ^ ((l15 >> 2) & 3) ^ (n)) & 3;    \
            bf[n] = *(const s16x8*)&bsU[(w * 64 + n * 16 + l15) * BROWE        \
                                        + T_ * 32 + rs_ * 8];                  \
        }                                                                      \
        __builtin_amdgcn_s_setprio(1);                                         \
        _Pragma("unroll")                                                      \
        for (int m = 0; m < 2; ++m)                                            \
            _Pragma("unroll")                                                  \
            for (int n = 0; n < 4; ++n)                                        \
                acc[m][n] = __builtin_amdgcn_mfma_f32_16x16x32_bf16(           \
                                afb[buf_][m], bf[n], acc[m][n], 0, 0, 0);      \
        __builtin_amdgcn_s_setprio(0);                                         \
        __builtin_amdgcn_sched_barrier(0);                                     \
        if constexpr (gn_ < NITER) {                                           \
            float ca_ = cfA[kk_], cb_ = cfB[kk_];                              \
            u32x4 ua_, ub_;                                                    \
            ua_[0] = cvt_pk_bf16(ca_*qa0_[0], ca_*qa0_[1]);                    \
            ua_[1] = cvt_pk_bf16(ca_*qa0_[2], ca_*qa0_[3]);                    \
            ua_[2] = cvt_pk_bf16(ca_*qa1_[0], ca_*qa1_[1]);                    \
            ua_[3] = cvt_pk_bf16(ca_*qa1_[2], ca_*qa1_[3]);                    \
            ub_[0] = cvt_pk_bf16(cb_*qb0_[0], cb_*qb0_[1]);                    \
            ub_[1] = cvt_pk_bf16(cb_*qb0_[2], cb_*qb0_[3]);                    \
            ub_[2] = cvt_pk_bf16(cb_*qb1_[0], cb_*qb1_[1]);                    \
            ub_[3] = cvt_pk_bf16(cb_*qb1_[2], cb_*qb1_[3]);                    \
            afb[nb_][0] = __builtin_bit_cast(s16x8, ua_);                      \
            afb[nb_][1] = __builtin_bit_cast(s16x8, ub_);                      \
        }                                                                      \
    }

// EPI for positions 0..3: c = mg*160 + P*32 + ... <= 607 < 630, so stores
// UNCONDITIONAL. nt + 64B direct-from-reg (optimal per R2-R6 matrix).
#define EPI(P_)                                                                \
    {                                                                          \
        _Pragma("unroll")                                                      \
        for (int m = 0; m < 2; ++m) {                                          \
            _Pragma("unroll")                                                  \
            for (int r = 0; r < 4; ++r) {                                      \
                int c = mg * 160 + (P_) * 32 + m * 16 + lhi * 4 + r;           \
                float t_ = tvl[c];                                             \
                float ct1 = -t_, ct2 = 0.5f * t_ * t_;                         \
                float ct3 = -(1.0f / 6.0f) * t_ * t_ * t_;                     \
                float* orow = out + ((size_t)bz * NCH + c) * HW + n0           \
                              + w * 64 + l15;                                  \
                _Pragma("unroll")                                              \
                for (int n = 0; n < 4; ++n) {                                  \
                    float base = gg[n][0] + ct1 * gg[n][1]                     \
                               + ct2 * gg[n][2] + ct3 * gg[n][3];              \
                    __builtin_nontemporal_store(                               \
                        __expf(acc[m][n][r] + base), orow + n * 16);           \
                }                                                              \
            }                                                                  \
        }                                                                      \
        _Pragma("unroll")                                                      \
        for (int m = 0; m < 2; ++m)                                            \
            _Pragma("unroll")                                                  \
            for (int n = 0; n < 4; ++n) acc[m][n] = (f32x4){0.f,0.f,0.f,0.f};  \
    }

    ITER(0)  ITER(1)  ITER(2)  ITER(3)  ITER(4)  ITER(5)
    ITER(6)  ITER(7)  ITER(8)  ITER(9)
    COEF(1)                       // prefetch enters position 1 at G=10
    ITER(10) ITER(11)
    EPI(0)
    ITER(12) ITER(13) ITER(14) ITER(15) ITER(16) ITER(17)
    ITER(18) ITER(19) ITER(20) ITER(21)
    COEF(2)
    ITER(22) ITER(23)
    EPI(1)
    ITER(24) ITER(25) ITER(26) ITER(27) ITER(28) ITER(29)
    ITER(30) ITER(31) ITER(32) ITER(33)
    COEF(3)
    ITER(34) ITER(35)
    EPI(2)
    ITER(36) ITER(37) ITER(38) ITER(39) ITER(40) ITER(41)
    ITER(42) ITER(43) ITER(44) ITER(45)
    COEF(4)
    ITER(46) ITER(47)
    EPI(3)
    ITER(48) ITER(49) ITER(50) ITER(51) ITER(52) ITER(53)
    ITER(54) ITER(55) ITER(56) ITER(57) ITER(58) ITER(59)

    // ---- terminal EPI (position 4: rows 608..639 region, guarded).
    //      Rows >= 630 have zero A-coeffs (b-factor) -> acc garbage-free;
    //      stores guarded anyway. ----
    {
        #pragma unroll
        for (int m = 0; m < 2; ++m) {
            #pragma unroll
            for (int r = 0; r < 4; ++r) {
                int c = mg * 160 + 4 * 32 + m * 16 + lhi * 4 + r;
                if (c < NCH) {
                    float t_ = tvl[c];
                    float ct1 = -t_, ct2 = 0.5f * t_ * t_;
                    float ct3 = -(1.0f / 6.0f) * t_ * t_ * t_;
                    float* orow = out + ((size_t)bz * NCH + c) * HW + n0
                                  + w * 64 + l15;
                    #pragma unroll
                    for (int n = 0; n < 4; ++n) {
                        float base = gg[n][0] + ct1 * gg[n][1]
                                   + ct2 * gg[n][2] + ct3 * gg[n][3];
                        __builtin_nontemporal_store(
                            __expf(acc[m][n][r] + base), orow + n * 16);
                    }
                }
            }
        }
    }

#undef EPI
#undef ITER
#undef AFINIT
#undef COEF
#undef BOFF
}

extern "C" void kernel_launch(void* const* d_in, const int* in_sizes, int n_in,
                              void* d_out, int out_size, void* d_ws, size_t ws_size,
                              hipStream_t stream) {
    const float* theta_global = (const float*)d_in[0];  // [2,4,128,128]
    const float* theta_dir    = (const float*)d_in[1];  // [2,64,6,128,128]
    const float* t_vec        = (const float*)d_in[2];  // [630]
    const float* b_vec        = (const float*)d_in[3];  // [630]
    const float* P            = (const float*)d_in[4];  // [630,64]
    float* out = (float*)d_out;

    (void)d_ws; (void)ws_size;   // workspace no longer needed

    (void)hipFuncSetAttribute((const void*)fused_gemm,
                              hipFuncAttributeMaxDynamicSharedMemorySize,
                              LDS_TOTAL);

    fused_gemm<<<dim3(HW / PANEL, BATCH), 512, LDS_TOTAL, stream>>>(
        P, theta_dir, t_vec, b_vec, theta_global, out);
}

// Round 9
// 34.605 us; speedup vs baseline: 1.9242x; 1.9242x over previous
//
#include <hip/hip_runtime.h>
#include <math.h>

#define BATCH 2
#define NDIRS 64
#define NCH   630
#define MPAD  640
#define HW    16384         // 128*128
#define KDIR  384           // 64 dirs * 6 moments
#define NT    12            // k-steps of 32
#define PANEL 128           // px per block (512B HBM read segments)
#define NPOSW 5             // m-positions (32 rows) per wave
#define NITER (NPOSW * NT)  // 60
#define BROWE 392           // Bs row stride in ushorts (784B)

// LDS layout (dynamic, 104960 B; 1 block/CU, 8 waves)
#define BS_OFF 0            // 128 * 392 * 2      = 100352
#define TV_OFF 100352       // 640 * 4            =   2560
#define TG_OFF 102912       // 4 * 128 * 4        =   2048
#define LDS_TOTAL 104960

typedef float f32x4 __attribute__((ext_vector_type(4)));
typedef short s16x8 __attribute__((ext_vector_type(8)));
typedef uint  u32x4 __attribute__((ext_vector_type(4)));

__device__ __forceinline__ uint cvt_pk_bf16(float lo, float hi) {
    uint r;
    asm("v_cvt_pk_bf16_f32 %0, %1, %2" : "=v"(r) : "v"(lo), "v"(hi));
    return r;
}

// nontemporal 16B load: TD stream has ZERO intra-kernel reuse.
__device__ __forceinline__ f32x4 ntload(const float* p) {
    return __builtin_nontemporal_load((const f32x4*)p);
}

// ---------------------------------------------------------------------------
// SINGLE fused kernel (R9). R8's 71us regression was vmcnt in-order
// coupling: per-iter P-loads consumed same-iter after the EPI store burst
// forced vmcnt(0) = full store drain EVERY iteration (+25-30us). Fix
// exploits the k'-permutation fully: per lane, a whole position's A-data
// is only TWO 32-float P windows per channel row (d0 = (ti&1)*32 + lhi*8;
// only the parity of ti varies). So:
//   - t/b scalars for all 5 positions hoisted ONCE at kernel start (20 reg)
//   - per position, 8 dwordx4 P loads -> qaE/qaO/qbE/qbO (32 reg), issued
//     at the position boundary BEFORE that position's EPI stores
//   - steady-state loop has ZERO vmem loads: 4 ds_read_b128 + 24 VALU
//     (16 mul + 8 cvt_pk A-frag gen) + 8 MFMA. No wait can couple to the
//     store queue. afb stays triple-buffered 2 iters ahead (pure VALU).
// B-staging, EPI (nt+64B direct stores, optimal per R2-R6 matrix), and
// the k'-space TD row mapping are unchanged from R8 (correctness-proven).
// prep_kernel + W2b workspace remain deleted (single dispatch).
// ---------------------------------------------------------------------------
__global__ __launch_bounds__(512, 2) void fused_gemm(
        const float* __restrict__ P,      // [NCH][64] f32 (L2-resident)
        const float* __restrict__ TD,     // [B][KDIR][HW] f32 (theta_dir)
        const float* __restrict__ t_vec,  // [NCH]
        const float* __restrict__ b_vec,  // [NCH]
        const float* __restrict__ TG,     // [B][4][HW]
        float* __restrict__ out)          // [B][NCH][HW]
{
    extern __shared__ char lds[];

    const int nt_ = blockIdx.x;           // 0..127 (128-px panel)
    const int bz  = blockIdx.y;           // 0..1
    const int n0  = nt_ * PANEL;

    const int tid  = threadIdx.x;         // 0..511
    const int lane = tid & 63;
    const int wv   = tid >> 6;            // 0..7
    const int mg   = wv & 3;              // A row group (c = mg*160 + ...)
    const int w    = wv >> 2;             // px half (0/1)
    const int l15 = lane & 15, lhi = lane >> 4;
    const int lhi8 = lhi << 3;

    ushort* bsU = (ushort*)(lds + BS_OFF);
    float*  tvl = (float*)(lds + TV_OFF);
    float*  tgl = (float*)(lds + TG_OFF);

    // ---- stage t_vec -> LDS (OOB-safe; for EPIs) ----
    tvl[tid] = t_vec[tid];
    if (tid < NCH - 512) tvl[tid + 512] = t_vec[tid + 512];
    else if (tid + 512 < MPAD) tvl[tid + 512] = 0.0f;
    // ---- stage TG (4 planes x 128 px) ----
    {
        int p = tid >> 7, px = tid & 127;
        tgl[p * PANEL + px] = TG[((size_t)bz * 4 + p) * HW + n0 + px];
    }

    // ---- hoist t/b for ALL positions once (before any stores exist) ----
    float tA[NPOSW], bA[NPOSW], tB[NPOSW], bB[NPOSW];
    #pragma unroll
    for (int p = 0; p < NPOSW; ++p) {
        int c0 = mg * 160 + p * 32 + l15;
        int cA = (c0 < NCH) ? c0 : (NCH - 1);
        int cB = (c0 + 16 < NCH) ? (c0 + 16) : (NCH - 1);
        tA[p] = t_vec[cA]; bA[p] = b_vec[cA];
        tB[p] = t_vec[cB]; bB[p] = b_vec[cB];
    }

    // ---- per-position A state: coeffs (VALU) + P windows (8 dwordx4) ----
    float cfA[6], cfB[6];
    f32x4 qaE0, qaE1, qaO0, qaO1, qbE0, qbE1, qbO0, qbO1;

#define COEF(P_)                                                               \
    {                                                                          \
        float t0_ = tA[P_], b0_ = bA[P_], t1_ = tB[P_], b1_ = bB[P_];          \
        cfA[0] = -b0_;                     cfB[0] = -b1_;                      \
        cfA[1] = t0_ * b0_;                cfB[1] = t1_ * b1_;                 \
        cfA[2] = 0.5f * b0_ * b0_;         cfB[2] = 0.5f * b1_ * b1_;          \
        cfA[3] = -0.5f * t0_ * t0_ * b0_;  cfB[3] = -0.5f * t1_ * t1_ * b1_;   \
        cfA[4] = -0.5f * t0_ * b0_ * b0_;  cfB[4] = -0.5f * t1_ * b1_ * b1_;   \
        cfA[5] = -(1.0f/6.0f) * b0_ * b0_ * b0_;                               \
        cfB[5] = -(1.0f/6.0f) * b1_ * b1_ * b1_;                               \
    }

#define QLOAD(P_)                                                              \
    {                                                                          \
        int c0_ = mg * 160 + (P_) * 32 + l15;                                  \
        int cA_ = (c0_ < NCH) ? c0_ : (NCH - 1);                               \
        int cB_ = (c0_ + 16 < NCH) ? (c0_ + 16) : (NCH - 1);                   \
        const float* pa_ = P + cA_ * 64 + lhi8;                                \
        const float* pb_ = P + cB_ * 64 + lhi8;                                \
        qaE0 = *(const f32x4*)(pa_);      qaE1 = *(const f32x4*)(pa_ + 4);     \
        qaO0 = *(const f32x4*)(pa_ + 32); qaO1 = *(const f32x4*)(pa_ + 36);    \
        qbE0 = *(const f32x4*)(pb_);      qbE1 = *(const f32x4*)(pb_ + 4);     \
        qbO0 = *(const f32x4*)(pb_ + 32); qbO1 = *(const f32x4*)(pb_ + 36);    \
    }

    s16x8 afb[3][2];

// build afb[NB_] for k-step TI_ of current position (pure VALU)
#define AFGEN(NB_, TI_)                                                        \
    {                                                                          \
        constexpr int kk_ = (TI_) >> 1;                                        \
        float ca_ = cfA[kk_], cb_ = cfB[kk_];                                  \
        f32x4 a0_, a1_, b0_, b1_;                                              \
        if constexpr (((TI_) & 1) == 0) {                                      \
            a0_ = qaE0; a1_ = qaE1; b0_ = qbE0; b1_ = qbE1;                    \
        } else {                                                               \
            a0_ = qaO0; a1_ = qaO1; b0_ = qbO0; b1_ = qbO1;                    \
        }                                                                      \
        u32x4 ua_, ub_;                                                        \
        ua_[0] = cvt_pk_bf16(ca_*a0_[0], ca_*a0_[1]);                          \
        ua_[1] = cvt_pk_bf16(ca_*a0_[2], ca_*a0_[3]);                          \
        ua_[2] = cvt_pk_bf16(ca_*a1_[0], ca_*a1_[1]);                          \
        ua_[3] = cvt_pk_bf16(ca_*a1_[2], ca_*a1_[3]);                          \
        ub_[0] = cvt_pk_bf16(cb_*b0_[0], cb_*b0_[1]);                          \
        ub_[1] = cvt_pk_bf16(cb_*b0_[2], cb_*b0_[3]);                          \
        ub_[2] = cvt_pk_bf16(cb_*b1_[0], cb_*b1_[1]);                          \
        ub_[3] = cvt_pk_bf16(cb_*b1_[2], cb_*b1_[3]);                          \
        afb[NB_][0] = __builtin_bit_cast(s16x8, ua_);                          \
        afb[NB_][1] = __builtin_bit_cast(s16x8, ub_);                          \
    }

    // ---- position-0 A state + first two iterations' fragments ----
    QLOAD(0)
    COEF(0)
    AFGEN(0, 0)
    AFGEN(1, 1)
    __builtin_amdgcn_sched_barrier(0);

    // ---- stage B panel: 12 k'-steps, depth-3 reg prefetch (NT loads) ----
    // step S stages k'-rows S*32 + {2kq2, 2kq2+1}; TD flat rows
    // 12*kq2 + (S&1)*192 + (S>>1) + {0, 6}. (k' = kk*64 + d permutation.)
    const int kq2 = mg * 4 + lhi;
    const int pg  = w * 16 + l15;
    const float* bT = TD + (size_t)bz * KDIR * HW + (size_t)(12 * kq2) * HW
                      + n0 + pg * 4;
    const int sxor = ((kq2 >> 2) ^ (pg & 3) ^ ((pg >> 2) & 3)) & 3;
    const int wbase = (kq2 & 3) * 2;      // uint pos within 8-ushort slot

#define BOFF(S) ((size_t)((((S) & 1) * 192) + ((S) >> 1)) * HW)

    {
        f32x4 lo0, hi0, lo1, hi1, lo2, hi2, lo3, hi3;
        lo0 = ntload(bT + BOFF(0));
        hi0 = ntload(bT + BOFF(0) + 6 * HW);
        lo1 = ntload(bT + BOFF(1));
        hi1 = ntload(bT + BOFF(1) + 6 * HW);
        lo2 = ntload(bT + BOFF(2));
        hi2 = ntload(bT + BOFF(2) + 6 * HW);

#define BSTEP(S, LC, HC, LN, HN)                                               \
        {                                                                      \
            if ((S) + 3 < NT) {                                                \
                LN = ntload(bT + BOFF((S) + 3));                               \
                HN = ntload(bT + BOFF((S) + 3) + 6 * HW);                      \
            }                                                                  \
            _Pragma("unroll")                                                  \
            for (int i = 0; i < 4; ++i) {                                      \
                uint w_ = cvt_pk_bf16(LC[i], HC[i]);                           \
                int s_ = (sxor ^ i) & 3;                                       \
                *(uint*)&bsU[(pg * 4 + i) * BROWE + (S) * 32 + s_ * 8 + wbase] = w_; \
            }                                                                  \
        }
        BSTEP(0, lo0, hi0, lo3, hi3)  BSTEP(1, lo1, hi1, lo0, hi0)
        BSTEP(2, lo2, hi2, lo1, hi1)  BSTEP(3, lo3, hi3, lo2, hi2)
        BSTEP(4, lo0, hi0, lo3, hi3)  BSTEP(5, lo1, hi1, lo0, hi0)
        BSTEP(6, lo2, hi2, lo1, hi1)  BSTEP(7, lo3, hi3, lo2, hi2)
        BSTEP(8, lo0, hi0, lo3, hi3)  BSTEP(9, lo1, hi1, lo0, hi0)
        BSTEP(10, lo2, hi2, lo1, hi1) BSTEP(11, lo3, hi3, lo2, hi2)
#undef BSTEP
    }

    // ---- single barrier: Bs/tv/tg visible ----
    asm volatile("s_waitcnt lgkmcnt(0)" ::: "memory");
    __builtin_amdgcn_s_barrier();
    __builtin_amdgcn_sched_barrier(0);

    // hoist TG values (wave covers its 64-px half: px = w*64 + n*16 + l15)
    float gg[4][4];
    #pragma unroll
    for (int n = 0; n < 4; ++n)
        #pragma unroll
        for (int p = 0; p < 4; ++p)
            gg[n][p] = tgl[p * PANEL + w * 64 + n * 16 + l15];

    f32x4 acc[2][4];
    #pragma unroll
    for (int m = 0; m < 2; ++m)
        #pragma unroll
        for (int n = 0; n < 4; ++n) acc[m][n] = (f32x4){0.f, 0.f, 0.f, 0.f};

    // ---- 60-iter pipeline; afb built 2 ahead, PURE VALU (no loop vmem) ----
#define ITER(G)                                                                \
    {                                                                          \
        constexpr int T_ = (G) % NT, buf_ = (G) % 3;                           \
        constexpr int gn_ = (G) + 2;                                           \
        s16x8 bf[4];                                                           \
        _Pragma("unroll")                                                      \
        for (int n = 0; n < 4; ++n) {                                          \
            const int rs_ = (lhi ^ (l15 & 3) ^ ((l15 >> 2) & 3) ^ (n)) & 3;    \
            bf[n] = *(const s16x8*)&bsU[(w * 64 + n * 16 + l15) * BROWE        \
                                        + T_ * 32 + rs_ * 8];                  \
        }                                                                      \
        __builtin_amdgcn_s_setprio(1);                                         \
        _Pragma("unroll")                                                      \
        for (int m = 0; m < 2; ++m)                                            \
            _Pragma("unroll")                                                  \
            for (int n = 0; n < 4; ++n)                                        \
                acc[m][n] = __builtin_amdgcn_mfma_f32_16x16x32_bf16(           \
                                afb[buf_][m], bf[n], acc[m][n], 0, 0, 0);      \
        __builtin_amdgcn_s_setprio(0);                                         \
        if constexpr (gn_ < NITER) {                                           \
            AFGEN(gn_ % 3, gn_ % NT)                                           \
        }                                                                      \
    }

// EPI for positions 0..3: c <= 607 < 630, stores UNCONDITIONAL.
// nt + 64B direct-from-reg (optimal per R2-R6 matrix).
#define EPI(P_)                                                                \
    {                                                                          \
        _Pragma("unroll")                                                      \
        for (int m = 0; m < 2; ++m) {                                          \
            _Pragma("unroll")                                                  \
            for (int r = 0; r < 4; ++r) {                                      \
                int c = mg * 160 + (P_) * 32 + m * 16 + lhi * 4 + r;           \
                float t_ = tvl[c];                                             \
                float ct1 = -t_, ct2 = 0.5f * t_ * t_;                         \
                float ct3 = -(1.0f / 6.0f) * t_ * t_ * t_;                     \
                float* orow = out + ((size_t)bz * NCH + c) * HW + n0           \
                              + w * 64 + l15;                                  \
                _Pragma("unroll")                                              \
                for (int n = 0; n < 4; ++n) {                                  \
                    float base = gg[n][0] + ct1 * gg[n][1]                     \
                               + ct2 * gg[n][2] + ct3 * gg[n][3];              \
                    __builtin_nontemporal_store(                               \
                        __expf(acc[m][n][r] + base), orow + n * 16);           \
                }                                                              \
            }                                                                  \
        }                                                                      \
        _Pragma("unroll")                                                      \
        for (int m = 0; m < 2; ++m)                                            \
            _Pragma("unroll")                                                  \
            for (int n = 0; n < 4; ++n) acc[m][n] = (f32x4){0.f,0.f,0.f,0.f};  \
    }

    // Boundary rule: QLOAD(p+1)+COEF(p+1) sit between ITER(9) and ITER(10)
    // of position p -- after the last use of position-p A state (ITER(9)
    // builds gn=11) and BEFORE EPI(p)'s store burst, so no loop wait ever
    // forces a store drain (vmcnt in-order).
    ITER(0)  ITER(1)  ITER(2)  ITER(3)  ITER(4)  ITER(5)
    ITER(6)  ITER(7)  ITER(8)  ITER(9)
    QLOAD(1) COEF(1)
    ITER(10) ITER(11)
    EPI(0)
    ITER(12) ITER(13) ITER(14) ITER(15) ITER(16) ITER(17)
    ITER(18) ITER(19) ITER(20) ITER(21)
    QLOAD(2) COEF(2)
    ITER(22) ITER(23)
    EPI(1)
    ITER(24) ITER(25) ITER(26) ITER(27) ITER(28) ITER(29)
    ITER(30) ITER(31) ITER(32) ITER(33)
    QLOAD(3) COEF(3)
    ITER(34) ITER(35)
    EPI(2)
    ITER(36) ITER(37) ITER(38) ITER(39) ITER(40) ITER(41)
    ITER(42) ITER(43) ITER(44) ITER(45)
    QLOAD(4) COEF(4)
    ITER(46) ITER(47)
    EPI(3)
    ITER(48) ITER(49) ITER(50) ITER(51) ITER(52) ITER(53)
    ITER(54) ITER(55) ITER(56) ITER(57) ITER(58) ITER(59)

    // ---- terminal EPI (position 4: rows 608..639 region, guarded).
    //      Rows >= 630 use clamped A rows -> garbage only in guarded-out
    //      channels (verified: R8 passed with identical clamping). ----
    {
        #pragma unroll
        for (int m = 0; m < 2; ++m) {
            #pragma unroll
            for (int r = 0; r < 4; ++r) {
                int c = mg * 160 + 4 * 32 + m * 16 + lhi * 4 + r;
                if (c < NCH) {
                    float t_ = tvl[c];
                    float ct1 = -t_, ct2 = 0.5f * t_ * t_;
                    float ct3 = -(1.0f / 6.0f) * t_ * t_ * t_;
                    float* orow = out + ((size_t)bz * NCH + c) * HW + n0
                                  + w * 64 + l15;
                    #pragma unroll
                    for (int n = 0; n < 4; ++n) {
                        float base = gg[n][0] + ct1 * gg[n][1]
                                   + ct2 * gg[n][2] + ct3 * gg[n][3];
                        __builtin_nontemporal_store(
                            __expf(acc[m][n][r] + base), orow + n * 16);
                    }
                }
            }
        }
    }

#undef EPI
#undef ITER
#undef AFGEN
#undef QLOAD
#undef COEF
#undef BOFF
}

extern "C" void kernel_launch(void* const* d_in, const int* in_sizes, int n_in,
                              void* d_out, int out_size, void* d_ws, size_t ws_size,
                              hipStream_t stream) {
    const float* theta_global = (const float*)d_in[0];  // [2,4,128,128]
    const float* theta_dir    = (const float*)d_in[1];  // [2,64,6,128,128]
    const float* t_vec        = (const float*)d_in[2];  // [630]
    const float* b_vec        = (const float*)d_in[3];  // [630]
    const float* P            = (const float*)d_in[4];  // [630,64]
    float* out = (float*)d_out;

    (void)d_ws; (void)ws_size;   // workspace not needed (single dispatch)

    (void)hipFuncSetAttribute((const void*)fused_gemm,
                              hipFuncAttributeMaxDynamicSharedMemorySize,
                              LDS_TOTAL);

    fused_gemm<<<dim3(HW / PANEL, BATCH), 512, LDS_TOTAL, stream>>>(
        P, theta_dir, t_vec, b_vec, theta_global, out);
}

// Round 10
// 33.003 us; speedup vs baseline: 2.0176x; 1.0485x over previous
//
#include <hip/hip_runtime.h>
#include <math.h>

#define BATCH 2
#define NDIRS 64
#define NCH   630
#define MPAD  640
#define HW    16384         // 128*128
#define KDIR  384           // 64 dirs * 6 moments
#define NT    12            // k-steps of 32
#define PANEL 128           // px per block (512B HBM read segments)
#define NPOSW 5             // m-positions (32 rows) per wave
#define NITER (NPOSW * NT)  // 60
#define BROWE 392           // Bs row stride in ushorts (784B)

// LDS layout (dynamic, 104960 B; 1 block/CU, 8 waves)
#define BS_OFF 0            // 128 * 392 * 2      = 100352
#define TV_OFF 100352       // 640 * 4            =   2560
#define TG_OFF 102912       // 4 * 128 * 4        =   2048
#define LDS_TOTAL 104960

typedef float f32x4 __attribute__((ext_vector_type(4)));
typedef short s16x8 __attribute__((ext_vector_type(8)));
typedef uint  u32x4 __attribute__((ext_vector_type(4)));

__device__ __forceinline__ uint cvt_pk_bf16(float lo, float hi) {
    uint r;
    asm("v_cvt_pk_bf16_f32 %0, %1, %2" : "=v"(r) : "v"(lo), "v"(hi));
    return r;
}

// nontemporal 16B load: TD stream has ZERO intra-kernel reuse.
__device__ __forceinline__ f32x4 ntload(const float* p) {
    return __builtin_nontemporal_load((const f32x4*)p);
}

// ---------------------------------------------------------------------------
// SINGLE fused kernel (R10 = R9 champion + bank-conflict-free slot swizzle).
// R8's PMC showed SQ_LDS_BANK_CONFLICT = 6.09M. Bank model (784B row = 4
// words mod 32): staging writes are 2 lanes/bank (free); the bf
// ds_read_b128 were aggregate-balanced but PER 8-LANE PHASE collided
// (old slot s = k8^(px&3)^((px>>2)&3): lanes 0-7 hit groups
// {0,2,4,6,5,5,1,1}) -> ~12 extra cyc/read x 491k reads = the 6.09M.
// New slot function: s = k8 ^ ((px>>4)&3).
//   read:  rs = (lhi ^ n)&3  -- constant per 8-lane phase -> bank group
//          (l15&7)+rs mod 8 is a rotation -> BIJECTIVE, zero conflicts.
//   write: s_ = (mg ^ ((l15>>2)&3))&3 (i-independent); distribution
//          stays exactly 2 lanes/bank = free (m136).
// slot(px_r, lhi) = rs re-verified -> MFMA operands bit-identical.
// Everything else unchanged from R9: vmem-free loop (A from P windows in
// VGPR, rebuilt per iter as pure VALU), QLOAD/COEF at position boundaries
// BEFORE the EPI store burst (vmcnt in-order safety), nt+64B stores.
// ---------------------------------------------------------------------------
__global__ __launch_bounds__(512, 2) void fused_gemm(
        const float* __restrict__ P,      // [NCH][64] f32 (L2-resident)
        const float* __restrict__ TD,     // [B][KDIR][HW] f32 (theta_dir)
        const float* __restrict__ t_vec,  // [NCH]
        const float* __restrict__ b_vec,  // [NCH]
        const float* __restrict__ TG,     // [B][4][HW]
        float* __restrict__ out)          // [B][NCH][HW]
{
    extern __shared__ char lds[];

    const int nt_ = blockIdx.x;           // 0..127 (128-px panel)
    const int bz  = blockIdx.y;           // 0..1
    const int n0  = nt_ * PANEL;

    const int tid  = threadIdx.x;         // 0..511
    const int lane = tid & 63;
    const int wv   = tid >> 6;            // 0..7
    const int mg   = wv & 3;              // A row group (c = mg*160 + ...)
    const int w    = wv >> 2;             // px half (0/1)
    const int l15 = lane & 15, lhi = lane >> 4;
    const int lhi8 = lhi << 3;

    ushort* bsU = (ushort*)(lds + BS_OFF);
    float*  tvl = (float*)(lds + TV_OFF);
    float*  tgl = (float*)(lds + TG_OFF);

    // ---- stage t_vec -> LDS (OOB-safe; for EPIs) ----
    tvl[tid] = t_vec[tid];
    if (tid < NCH - 512) tvl[tid + 512] = t_vec[tid + 512];
    else if (tid + 512 < MPAD) tvl[tid + 512] = 0.0f;
    // ---- stage TG (4 planes x 128 px) ----
    {
        int p = tid >> 7, px = tid & 127;
        tgl[p * PANEL + px] = TG[((size_t)bz * 4 + p) * HW + n0 + px];
    }

    // ---- hoist t/b for ALL positions once (before any stores exist) ----
    float tA[NPOSW], bA[NPOSW], tB[NPOSW], bB[NPOSW];
    #pragma unroll
    for (int p = 0; p < NPOSW; ++p) {
        int c0 = mg * 160 + p * 32 + l15;
        int cA = (c0 < NCH) ? c0 : (NCH - 1);
        int cB = (c0 + 16 < NCH) ? (c0 + 16) : (NCH - 1);
        tA[p] = t_vec[cA]; bA[p] = b_vec[cA];
        tB[p] = t_vec[cB]; bB[p] = b_vec[cB];
    }

    // ---- per-position A state: coeffs (VALU) + P windows (8 dwordx4) ----
    float cfA[6], cfB[6];
    f32x4 qaE0, qaE1, qaO0, qaO1, qbE0, qbE1, qbO0, qbO1;

#define COEF(P_)                                                               \
    {                                                                          \
        float t0_ = tA[P_], b0_ = bA[P_], t1_ = tB[P_], b1_ = bB[P_];          \
        cfA[0] = -b0_;                     cfB[0] = -b1_;                      \
        cfA[1] = t0_ * b0_;                cfB[1] = t1_ * b1_;                 \
        cfA[2] = 0.5f * b0_ * b0_;         cfB[2] = 0.5f * b1_ * b1_;          \
        cfA[3] = -0.5f * t0_ * t0_ * b0_;  cfB[3] = -0.5f * t1_ * t1_ * b1_;   \
        cfA[4] = -0.5f * t0_ * b0_ * b0_;  cfB[4] = -0.5f * t1_ * b1_ * b1_;   \
        cfA[5] = -(1.0f/6.0f) * b0_ * b0_ * b0_;                               \
        cfB[5] = -(1.0f/6.0f) * b1_ * b1_ * b1_;                               \
    }

#define QLOAD(P_)                                                              \
    {                                                                          \
        int c0_ = mg * 160 + (P_) * 32 + l15;                                  \
        int cA_ = (c0_ < NCH) ? c0_ : (NCH - 1);                               \
        int cB_ = (c0_ + 16 < NCH) ? (c0_ + 16) : (NCH - 1);                   \
        const float* pa_ = P + cA_ * 64 + lhi8;                                \
        const float* pb_ = P + cB_ * 64 + lhi8;                                \
        qaE0 = *(const f32x4*)(pa_);      qaE1 = *(const f32x4*)(pa_ + 4);     \
        qaO0 = *(const f32x4*)(pa_ + 32); qaO1 = *(const f32x4*)(pa_ + 36);    \
        qbE0 = *(const f32x4*)(pb_);      qbE1 = *(const f32x4*)(pb_ + 4);     \
        qbO0 = *(const f32x4*)(pb_ + 32); qbO1 = *(const f32x4*)(pb_ + 36);    \
    }

    s16x8 afb[3][2];

// build afb[NB_] for k-step TI_ of current position (pure VALU)
#define AFGEN(NB_, TI_)                                                        \
    {                                                                          \
        constexpr int kk_ = (TI_) >> 1;                                        \
        float ca_ = cfA[kk_], cb_ = cfB[kk_];                                  \
        f32x4 a0_, a1_, b0_, b1_;                                              \
        if constexpr (((TI_) & 1) == 0) {                                      \
            a0_ = qaE0; a1_ = qaE1; b0_ = qbE0; b1_ = qbE1;                    \
        } else {                                                               \
            a0_ = qaO0; a1_ = qaO1; b0_ = qbO0; b1_ = qbO1;                    \
        }                                                                      \
        u32x4 ua_, ub_;                                                        \
        ua_[0] = cvt_pk_bf16(ca_*a0_[0], ca_*a0_[1]);                          \
        ua_[1] = cvt_pk_bf16(ca_*a0_[2], ca_*a0_[3]);                          \
        ua_[2] = cvt_pk_bf16(ca_*a1_[0], ca_*a1_[1]);                          \
        ua_[3] = cvt_pk_bf16(ca_*a1_[2], ca_*a1_[3]);                          \
        ub_[0] = cvt_pk_bf16(cb_*b0_[0], cb_*b0_[1]);                          \
        ub_[1] = cvt_pk_bf16(cb_*b0_[2], cb_*b0_[3]);                          \
        ub_[2] = cvt_pk_bf16(cb_*b1_[0], cb_*b1_[1]);                          \
        ub_[3] = cvt_pk_bf16(cb_*b1_[2], cb_*b1_[3]);                          \
        afb[NB_][0] = __builtin_bit_cast(s16x8, ua_);                          \
        afb[NB_][1] = __builtin_bit_cast(s16x8, ub_);                          \
    }

    // ---- position-0 A state + first two iterations' fragments ----
    QLOAD(0)
    COEF(0)
    AFGEN(0, 0)
    AFGEN(1, 1)
    __builtin_amdgcn_sched_barrier(0);

    // ---- stage B panel: 12 k'-steps, depth-3 reg prefetch (NT loads) ----
    // step S stages k'-rows S*32 + {2kq2, 2kq2+1}; TD flat rows
    // 12*kq2 + (S&1)*192 + (S>>1) + {0, 6}. (k' = kk*64 + d permutation.)
    const int kq2 = mg * 4 + lhi;
    const int pg  = w * 16 + l15;
    const float* bT = TD + (size_t)bz * KDIR * HW + (size_t)(12 * kq2) * HW
                      + n0 + pg * 4;
    // NEW slot function: s = k8 ^ ((px>>4)&3). k8 = kq2>>2 = mg;
    // (px>>4)&3 = (pg>>2)&3. i-independent -> same slot for all 4 px.
    const int swr = ((kq2 >> 2) ^ ((pg >> 2) & 3)) & 3;
    const int wbase = (kq2 & 3) * 2;      // uint pos within 8-ushort slot

#define BOFF(S) ((size_t)((((S) & 1) * 192) + ((S) >> 1)) * HW)

    {
        f32x4 lo0, hi0, lo1, hi1, lo2, hi2, lo3, hi3;
        lo0 = ntload(bT + BOFF(0));
        hi0 = ntload(bT + BOFF(0) + 6 * HW);
        lo1 = ntload(bT + BOFF(1));
        hi1 = ntload(bT + BOFF(1) + 6 * HW);
        lo2 = ntload(bT + BOFF(2));
        hi2 = ntload(bT + BOFF(2) + 6 * HW);

#define BSTEP(S, LC, HC, LN, HN)                                               \
        {                                                                      \
            if ((S) + 3 < NT) {                                                \
                LN = ntload(bT + BOFF((S) + 3));                               \
                HN = ntload(bT + BOFF((S) + 3) + 6 * HW);                      \
            }                                                                  \
            _Pragma("unroll")                                                  \
            for (int i = 0; i < 4; ++i) {                                      \
                uint w_ = cvt_pk_bf16(LC[i], HC[i]);                           \
                *(uint*)&bsU[(pg * 4 + i) * BROWE + (S) * 32 + swr * 8 + wbase] = w_; \
            }                                                                  \
        }
        BSTEP(0, lo0, hi0, lo3, hi3)  BSTEP(1, lo1, hi1, lo0, hi0)
        BSTEP(2, lo2, hi2, lo1, hi1)  BSTEP(3, lo3, hi3, lo2, hi2)
        BSTEP(4, lo0, hi0, lo3, hi3)  BSTEP(5, lo1, hi1, lo0, hi0)
        BSTEP(6, lo2, hi2, lo1, hi1)  BSTEP(7, lo3, hi3, lo2, hi2)
        BSTEP(8, lo0, hi0, lo3, hi3)  BSTEP(9, lo1, hi1, lo0, hi0)
        BSTEP(10, lo2, hi2, lo1, hi1) BSTEP(11, lo3, hi3, lo2, hi2)
#undef BSTEP
    }

    // ---- single barrier: Bs/tv/tg visible ----
    asm volatile("s_waitcnt lgkmcnt(0)" ::: "memory");
    __builtin_amdgcn_s_barrier();
    __builtin_amdgcn_sched_barrier(0);

    // hoist TG values (wave covers its 64-px half: px = w*64 + n*16 + l15)
    float gg[4][4];
    #pragma unroll
    for (int n = 0; n < 4; ++n)
        #pragma unroll
        for (int p = 0; p < 4; ++p)
            gg[n][p] = tgl[p * PANEL + w * 64 + n * 16 + l15];

    f32x4 acc[2][4];
    #pragma unroll
    for (int m = 0; m < 2; ++m)
        #pragma unroll
        for (int n = 0; n < 4; ++n) acc[m][n] = (f32x4){0.f, 0.f, 0.f, 0.f};

    // ---- 60-iter pipeline; afb built 2 ahead, PURE VALU (no loop vmem) ----
    // bf read slot: rs = slot(px_r, lhi) = (lhi ^ n)&3 -- constant per
    // 8-lane phase -> conflict-free ds_read_b128.
#define ITER(G)                                                                \
    {                                                                          \
        constexpr int T_ = (G) % NT, buf_ = (G) % 3;                           \
        constexpr int gn_ = (G) + 2;                                           \
        s16x8 bf[4];                                                           \
        _Pragma("unroll")                                                      \
        for (int n = 0; n < 4; ++n) {                                          \
            const int rs_ = (lhi ^ n) & 3;                                     \
            bf[n] = *(const s16x8*)&bsU[(w * 64 + n * 16 + l15) * BROWE        \
                                        + T_ * 32 + rs_ * 8];                  \
        }                                                                      \
        __builtin_amdgcn_s_setprio(1);                                         \
        _Pragma("unroll")                                                      \
        for (int m = 0; m < 2; ++m)                                            \
            _Pragma("unroll")                                                  \
            for (int n = 0; n < 4; ++n)                                        \
                acc[m][n] = __builtin_amdgcn_mfma_f32_16x16x32_bf16(           \
                                afb[buf_][m], bf[n], acc[m][n], 0, 0, 0);      \
        __builtin_amdgcn_s_setprio(0);                                         \
        if constexpr (gn_ < NITER) {                                           \
            AFGEN(gn_ % 3, gn_ % NT)                                           \
        }                                                                      \
    }

// EPI for positions 0..3: c <= 607 < 630, stores UNCONDITIONAL.
// nt + 64B direct-from-reg (optimal per R2-R6 matrix).
#define EPI(P_)                                                                \
    {                                                                          \
        _Pragma("unroll")                                                      \
        for (int m = 0; m < 2; ++m) {                                          \
            _Pragma("unroll")                                                  \
            for (int r = 0; r < 4; ++r) {                                      \
                int c = mg * 160 + (P_) * 32 + m * 16 + lhi * 4 + r;           \
                float t_ = tvl[c];                                             \
                float ct1 = -t_, ct2 = 0.5f * t_ * t_;                         \
                float ct3 = -(1.0f / 6.0f) * t_ * t_ * t_;                     \
                float* orow = out + ((size_t)bz * NCH + c) * HW + n0           \
                              + w * 64 + l15;                                  \
                _Pragma("unroll")                                              \
                for (int n = 0; n < 4; ++n) {                                  \
                    float base = gg[n][0] + ct1 * gg[n][1]                     \
                               + ct2 * gg[n][2] + ct3 * gg[n][3];              \
                    __builtin_nontemporal_store(                               \
                        __expf(acc[m][n][r] + base), orow + n * 16);           \
                }                                                              \
            }                                                                  \
        }                                                                      \
        _Pragma("unroll")                                                      \
        for (int m = 0; m < 2; ++m)                                            \
            _Pragma("unroll")                                                  \
            for (int n = 0; n < 4; ++n) acc[m][n] = (f32x4){0.f,0.f,0.f,0.f};  \
    }

    // Boundary rule: QLOAD(p+1)+COEF(p+1) sit between ITER(9) and ITER(10)
    // of position p -- after the last use of position-p A state and BEFORE
    // EPI(p)'s store burst (vmcnt in-order safety, proven R8->R9).
    ITER(0)  ITER(1)  ITER(2)  ITER(3)  ITER(4)  ITER(5)
    ITER(6)  ITER(7)  ITER(8)  ITER(9)
    QLOAD(1) COEF(1)
    ITER(10) ITER(11)
    EPI(0)
    ITER(12) ITER(13) ITER(14) ITER(15) ITER(16) ITER(17)
    ITER(18) ITER(19) ITER(20) ITER(21)
    QLOAD(2) COEF(2)
    ITER(22) ITER(23)
    EPI(1)
    ITER(24) ITER(25) ITER(26) ITER(27) ITER(28) ITER(29)
    ITER(30) ITER(31) ITER(32) ITER(33)
    QLOAD(3) COEF(3)
    ITER(34) ITER(35)
    EPI(2)
    ITER(36) ITER(37) ITER(38) ITER(39) ITER(40) ITER(41)
    ITER(42) ITER(43) ITER(44) ITER(45)
    QLOAD(4) COEF(4)
    ITER(46) ITER(47)
    EPI(3)
    ITER(48) ITER(49) ITER(50) ITER(51) ITER(52) ITER(53)
    ITER(54) ITER(55) ITER(56) ITER(57) ITER(58) ITER(59)

    // ---- terminal EPI (position 4: rows 608..639 region, guarded) ----
    {
        #pragma unroll
        for (int m = 0; m < 2; ++m) {
            #pragma unroll
            for (int r = 0; r < 4; ++r) {
                int c = mg * 160 + 4 * 32 + m * 16 + lhi * 4 + r;
                if (c < NCH) {
                    float t_ = tvl[c];
                    float ct1 = -t_, ct2 = 0.5f * t_ * t_;
                    float ct3 = -(1.0f / 6.0f) * t_ * t_ * t_;
                    float* orow = out + ((size_t)bz * NCH + c) * HW + n0
                                  + w * 64 + l15;
                    #pragma unroll
                    for (int n = 0; n < 4; ++n) {
                        float base = gg[n][0] + ct1 * gg[n][1]
                                   + ct2 * gg[n][2] + ct3 * gg[n][3];
                        __builtin_nontemporal_store(
                            __expf(acc[m][n][r] + base), orow + n * 16);
                    }
                }
            }
        }
    }

#undef EPI
#undef ITER
#undef AFGEN
#undef QLOAD
#undef COEF
#undef BOFF
}

extern "C" void kernel_launch(void* const* d_in, const int* in_sizes, int n_in,
                              void* d_out, int out_size, void* d_ws, size_t ws_size,
                              hipStream_t stream) {
    const float* theta_global = (const float*)d_in[0];  // [2,4,128,128]
    const float* theta_dir    = (const float*)d_in[1];  // [2,64,6,128,128]
    const float* t_vec        = (const float*)d_in[2];  // [630]
    const float* b_vec        = (const float*)d_in[3];  // [630]
    const float* P            = (const float*)d_in[4];  // [630,64]
    float* out = (float*)d_out;

    (void)d_ws; (void)ws_size;   // workspace not needed (single dispatch)

    (void)hipFuncSetAttribute((const void*)fused_gemm,
                              hipFuncAttributeMaxDynamicSharedMemorySize,
                              LDS_TOTAL);

    fused_gemm<<<dim3(HW / PANEL, BATCH), 512, LDS_TOTAL, stream>>>(
        P, theta_dir, t_vec, b_vec, theta_global, out);
}